// Round 14
// baseline (2170.760 us; speedup 1.0000x reference)
//
#include <hip/hip_runtime.h>
#include <stdint.h>

typedef unsigned short u16;
typedef _Float16 half_t;
typedef __attribute__((ext_vector_type(4))) float f32x4;
typedef __attribute__((ext_vector_type(8))) _Float16 f16x8;

#define NS_A 3.4445f
#define NS_B -4.7750f
#define NS_C 2.0315f

// scales (exact powers of 2, folded into epilogues):
//   x stored as 64*x ; a stored as 4096*a ; bmat stored as 4096*bmat
#define SX      64.0f
#define INV_SX  (1.0f / 64.0f)
#define INV_SA  (1.0f / 4096.0f)

// ---- async global->LDS, 16B per lane (wave-uniform LDS base + lane*16 implicit)
typedef const __attribute__((address_space(1))) void* as1_cvp;
typedef __attribute__((address_space(3))) void* as3_vp;
#define GLOAD_LDS16(gp, lp) \
    __builtin_amdgcn_global_load_lds((as1_cvp)(const void*)(gp), (as3_vp)(void*)(lp), 16, 0, 0)

template <int N> __device__ __forceinline__ void vmwait() {
    if constexpr (N == 0)       asm volatile("s_waitcnt vmcnt(0)" ::: "memory");
    else if constexpr (N == 4)  asm volatile("s_waitcnt vmcnt(4)" ::: "memory");
    else if constexpr (N == 6)  asm volatile("s_waitcnt vmcnt(6)" ::: "memory");
    else if constexpr (N == 8)  asm volatile("s_waitcnt vmcnt(8)" ::: "memory");
    else if constexpr (N == 12) asm volatile("s_waitcnt vmcnt(12)" ::: "memory");
    else static_assert(N == 0, "unsupported vmcnt");
}

// =======================================================================
// NS GEMM (modes 0/1/2) — byte-identical to the verified R11 kernel
// (best NS measured: 24.3 us/GEMM). 64x128 block tile, 4 waves (2x2, wave
// 32x64), BK=64, ring R=3 (72 KB -> 2 blocks/CU), 2-D XCD chunk.
// Pipeline per K-step: reads(s); stage(s+2); vmwait(6); barrier;
//                      setprio(1) 16 MFMA setprio(0); barrier.
// LDS XOR swizzle (both-sides, proven 0-conflict).
// =======================================================================
template <int MODE>
__global__ __launch_bounds__(256, 2) void gemm_ns(
    const half_t* __restrict__ A, const half_t* __restrict__ B,
    const half_t* __restrict__ aux,
    void* __restrict__ outp, half_t* __restrict__ outpT,
    int M, int N, int K)
{
    __shared__ half_t As[3][64 * 64];
    __shared__ half_t Bs[3][128 * 64];
    const int tid  = threadIdx.x;
    const int wid  = tid >> 6;
    const int lane = tid & 63;
    const int wr = wid >> 1, wc = wid & 1;

    const int xcd = blockIdx.x & 7;
    const int ii  = blockIdx.x >> 3;               // [0, 64)
    const int brow = ((xcd & 1) * 16 + (ii >> 2)) * 64;
    const int bcol = ((xcd >> 1) * 4 + (ii & 3)) * 128;

    f32x4 acc[2][4] = {};

    const int r0   = tid >> 3;
    const int csrc = ((tid & 7) ^ ((tid >> 3) & 7)) * 8;
    const half_t* gA = A + (size_t)(brow + r0) * K + csrc;
    const half_t* gB = B + (size_t)(bcol + r0) * K + csrc;

    auto stage = [&](int slot, int kt) {
#pragma unroll
        for (int j = 0; j < 2; ++j)   // A: 64 rows
            GLOAD_LDS16(gA + (size_t)(j * 32) * K + kt, &As[slot][(j * 256 + wid * 64) * 8]);
#pragma unroll
        for (int j = 0; j < 4; ++j)   // B: 128 rows
            GLOAD_LDS16(gB + (size_t)(j * 32) * K + kt, &Bs[slot][(j * 256 + wid * 64) * 8]);
    };

    f16x8 af[2][2], bf[4][2];
    auto reads = [&](int slot) {
#pragma unroll
        for (int m = 0; m < 2; ++m) {
            const int row = wr * 32 + m * 16 + (lane & 15);
#pragma unroll
            for (int kk = 0; kk < 2; ++kk) {
                const int cc = (kk * 4 + (lane >> 4)) ^ (row & 7);
                af[m][kk] = *(const f16x8*)&As[slot][row * 64 + cc * 8];
            }
        }
#pragma unroll
        for (int n = 0; n < 4; ++n) {
            const int row = wc * 64 + n * 16 + (lane & 15);
#pragma unroll
            for (int kk = 0; kk < 2; ++kk) {
                const int cc = (kk * 4 + (lane >> 4)) ^ (row & 7);
                bf[n][kk] = *(const f16x8*)&Bs[slot][row * 64 + cc * 8];
            }
        }
    };
    auto mfma = [&]() {
        __builtin_amdgcn_s_setprio(1);
#pragma unroll
        for (int kk = 0; kk < 2; ++kk)
#pragma unroll
            for (int m = 0; m < 2; ++m)
#pragma unroll
                for (int n = 0; n < 4; ++n)
                    acc[m][n] = __builtin_amdgcn_mfma_f32_16x16x32_f16(af[m][kk], bf[n][kk], acc[m][n], 0, 0, 0);
        __builtin_amdgcn_s_setprio(0);
    };

    const int nsteps = K / 64;            // 32
    stage(0, 0);
    stage(1, 64);
    vmwait<6>();                          // certify slot 0
    __builtin_amdgcn_s_barrier();

    int s = 0;
    for (; s < nsteps - 2; ++s) {
        reads(s % 3);
        stage((s + 2) % 3, (s + 2) * 64);
        vmwait<6>();                      // certify slot s+1
        __builtin_amdgcn_s_barrier();
        mfma();
        __builtin_amdgcn_s_barrier();
    }
    reads(s % 3);                         // s = nsteps-2
    vmwait<0>();                          // certify last slot
    __builtin_amdgcn_s_barrier();
    mfma();
    __builtin_amdgcn_s_barrier();
    ++s;
    reads(s % 3);                         // s = nsteps-1
    mfma();

    // epilogue: C/D layout col = lane&15, row = (lane>>4)*4 + r
#pragma unroll
    for (int m = 0; m < 2; ++m) {
#pragma unroll
        for (int n = 0; n < 4; ++n) {
            const int row0 = brow + wr * 32 + m * 16 + (lane >> 4) * 4;
            const int col  = bcol + wc * 64 + n * 16 + (lane & 15);
#pragma unroll
            for (int r = 0; r < 4; ++r) {
                const size_t idx = (size_t)(row0 + r) * N + col;
                const float v = acc[m][n][r];
                if (MODE == 0) {
                    ((half_t*)outp)[idx] = (half_t)v;
                } else if (MODE == 1) {
                    ((half_t*)outp)[idx] = (half_t)(NS_B * (float)aux[idx] + NS_C * v * INV_SA);
                } else {
                    const half_t o = (half_t)(NS_A * (float)aux[idx] + v * INV_SA);
                    ((half_t*)outp)[idx] = o;
                    if (outpT) outpT[(size_t)col * M + row0 + r] = o;
                }
            }
        }
    }
}

// =======================================================================
// Final GEMM R14: out = A@B^T/64 + bias.  256x256 tile, 8 waves (2Mx4N,
// wave 128x64), BK=32, R=2 double-buffer -> 64 KB LDS -> TWO blocks/CU
// co-resident (VGPR capped at 128 via __launch_bounds__(512,4)).
// Per step s: stage(s+1 -> slot^1) issued FIRST (hides HBM latency under
// compute); compute(slot) = 12 ds_read + setprio 32-MFMA cluster;
// vmwait(0) + ONE barrier (certifies slot^1 AND fences this slot's reads
// before step s+1's stage overwrites it). Cross-block TLP (2 blocks/CU)
// covers the drain. Swizzle key (row>>1)&3 (proven 0-conflict, R8).
// =======================================================================
__global__ __launch_bounds__(512, 4) void gemm_fin(
    const half_t* __restrict__ A, const half_t* __restrict__ B,
    const float* __restrict__ bias, float* __restrict__ out,
    int M, int N, int K)
{
    __shared__ half_t As[2][256 * 32];
    __shared__ half_t Bs[2][256 * 32];
    const int tid  = threadIdx.x;
    const int wid  = tid >> 6;
    const int lane = tid & 63;
    const int wm = wid >> 2;
    const int wn = wid & 3;

    int bid = blockIdx.x;                 // gridDim.x % 8 == 0
    const int cpx = gridDim.x >> 3;
    bid = (bid & 7) * cpx + (bid >> 3);
    const int nbx  = N >> 8;
    const int brow = (bid / nbx) << 8;
    const int bcol = (bid % nbx) << 8;

    f32x4 acc[8][4] = {};

    const int r0   = tid >> 2;            // 4 chunks/row
    const int csrc = ((tid & 3) ^ ((tid >> 3) & 3)) * 8;
    const half_t* gA = A + (size_t)(brow + r0) * K + csrc;
    const half_t* gB = B + (size_t)(bcol + r0) * K + csrc;

    auto stage = [&](int slot, int kt) {
#pragma unroll
        for (int j = 0; j < 2; ++j)
            GLOAD_LDS16(gA + (size_t)(j * 128) * K + kt, &As[slot][(j * 512 + wid * 64) * 8]);
#pragma unroll
        for (int j = 0; j < 2; ++j)
            GLOAD_LDS16(gB + (size_t)(j * 128) * K + kt, &Bs[slot][(j * 512 + wid * 64) * 8]);
    };
    auto compute = [&](int slot) {
        f16x8 af[8], bf[4];
#pragma unroll
        for (int fr = 0; fr < 8; ++fr) {
            const int row = wm * 128 + fr * 16 + (lane & 15);
            af[fr] = *(const f16x8*)&As[slot][row * 32 + (((lane >> 4) ^ ((row >> 1) & 3)) * 8)];
        }
#pragma unroll
        for (int fc = 0; fc < 4; ++fc) {
            const int row = wn * 64 + fc * 16 + (lane & 15);
            bf[fc] = *(const f16x8*)&Bs[slot][row * 32 + (((lane >> 4) ^ ((row >> 1) & 3)) * 8)];
        }
        __builtin_amdgcn_s_setprio(1);
#pragma unroll
        for (int fr = 0; fr < 8; ++fr)
#pragma unroll
            for (int fc = 0; fc < 4; ++fc)
                acc[fr][fc] = __builtin_amdgcn_mfma_f32_16x16x32_f16(af[fr], bf[fc], acc[fr][fc], 0, 0, 0);
        __builtin_amdgcn_s_setprio(0);
    };

    const int nsteps = K >> 5;            // 64
    stage(0, 0);
    vmwait<0>();                          // certify slot 0
    __builtin_amdgcn_s_barrier();

    for (int s = 0; s < nsteps; ++s) {
        const int slot = s & 1;
        if (s + 1 < nsteps) stage(slot ^ 1, (s + 1) * 32);  // issue early
        compute(slot);
        if (s + 1 < nsteps) {
            vmwait<0>();                  // certify slot^1 (issued ~400cyc ago)
            __builtin_amdgcn_s_barrier(); // + fence this slot's reads
        }
    }

    // epilogue
#pragma unroll
    for (int fr = 0; fr < 8; ++fr) {
#pragma unroll
        for (int fc = 0; fc < 4; ++fc) {
            const int row0 = brow + wm * 128 + fr * 16 + (lane >> 4) * 4;
            const int col  = bcol + wn * 64 + fc * 16 + (lane & 15);
            const float bv = bias[col];
#pragma unroll
            for (int r = 0; r < 4; ++r)
                out[(size_t)(row0 + r) * N + col] = acc[fr][fc][r] * INV_SX + bv;
        }
    }
}

// ---- deterministic Frobenius-norm reduction (fixed order, no float atomics)
__global__ __launch_bounds__(256) void k_sumsq(const float* __restrict__ w,
                                               float* __restrict__ part, int n) {
    __shared__ float s[256];
    const int per  = n / 1024;
    const int base = blockIdx.x * per;
    float acc = 0.f;
    for (int i = threadIdx.x; i < per; i += 256) {
        float v = w[base + i];
        acc += v * v;
    }
    s[threadIdx.x] = acc;
    __syncthreads();
    for (int k = 128; k > 0; k >>= 1) {
        if (threadIdx.x < k) s[threadIdx.x] += s[threadIdx.x + k];
        __syncthreads();
    }
    if (threadIdx.x == 0) part[blockIdx.x] = s[0];
}

__global__ __launch_bounds__(256) void k_scalefin(const float* __restrict__ part,
                                                  float* __restrict__ scale) {
    __shared__ float s[256];
    float acc = 0.f;
    for (int i = threadIdx.x; i < 1024; i += 256) acc += part[i];
    s[threadIdx.x] = acc;
    __syncthreads();
    for (int k = 128; k > 0; k >>= 1) {
        if (threadIdx.x < k) s[threadIdx.x] += s[threadIdx.x + k];
        __syncthreads();
    }
    if (threadIdx.x == 0) scale[0] = SX / (sqrtf(s[0]) + 1e-7f);
}

// ---- x0_s = w * (64/(|w|+eps)) -> f16
__global__ __launch_bounds__(256) void k_scale_f16(const float* __restrict__ w,
                                                   const float* __restrict__ scale,
                                                   half_t* __restrict__ o, int n) {
    const int i = (blockIdx.x * 256 + threadIdx.x) * 4;
    if (i < n) {
        const float sc = scale[0];
        float4 v = *(const float4*)(w + i);
        o[i + 0] = (half_t)(v.x * sc);
        o[i + 1] = (half_t)(v.y * sc);
        o[i + 2] = (half_t)(v.z * sc);
        o[i + 3] = (half_t)(v.w * sc);
    }
}

// ---- f32 -> f16 cast
__global__ __launch_bounds__(256) void k_cast_f16(const float* __restrict__ w,
                                                  half_t* __restrict__ o, int n) {
    const int i = (blockIdx.x * 256 + threadIdx.x) * 4;
    if (i < n) {
        float4 v = *(const float4*)(w + i);
        o[i + 0] = (half_t)v.x;
        o[i + 1] = (half_t)v.y;
        o[i + 2] = (half_t)v.z;
        o[i + 3] = (half_t)v.w;
    }
}

// ---- 16-bit NxN transpose, 64x64 LDS tiles (+1 pad)
__global__ __launch_bounds__(256) void k_transpose(const u16* __restrict__ in,
                                                   u16* __restrict__ out, int n) {
    __shared__ u16 tile[64][65];
    const int bx = blockIdx.x * 64, by = blockIdx.y * 64;
    const int tx = threadIdx.x & 63, ty = threadIdx.x >> 6;
    for (int i = ty; i < 64; i += 4) tile[i][tx] = in[(size_t)(by + i) * n + bx + tx];
    __syncthreads();
    for (int i = ty; i < 64; i += 4) out[(size_t)(bx + i) * n + by + tx] = tile[tx][i];
}

extern "C" void kernel_launch(void* const* d_in, const int* in_sizes, int n_in,
                              void* d_out, int out_size, void* d_ws, size_t ws_size,
                              hipStream_t stream) {
    const float* x = (const float*)d_in[0];
    const float* w = (const float*)d_in[1];
    const float* b = (const float*)d_in[2];
    float* out = (float*)d_out;

    const int D  = 2048;
    const int Bm = in_sizes[0] / D;      // 16384
    const int WN = D * D;
    const int XN = Bm * D;

    const size_t matB = (size_t)WN * 2;
    const bool pingpong = ws_size >= 8192 + 6 * matB + (size_t)XN * 2;

    char* ws = (char*)d_ws;
    float* part  = (float*)ws;
    float* scale = part + 1024;
    half_t* xb0  = (half_t*)(ws + 8192);
    half_t* xb1  = xb0 + WN;
    half_t* xbTa = xb1 + WN;
    half_t* xbTb = pingpong ? (xbTa + WN) : xbTa;
    half_t* amat = xbTb + WN;
    half_t* bmat = amat + WN;
    half_t* xinb = bmat + WN;

    // 1. frobenius norm -> scale; x0_s = 64*w/(|w|+eps) in f16
    k_sumsq<<<1024, 256, 0, stream>>>(w, part, WN);
    k_scalefin<<<1, 256, 0, stream>>>(part, scale);
    k_scale_f16<<<WN / 4 / 256, 256, 0, stream>>>(w, scale, xb0, WN);

    // 2. x -> f16 (final GEMM operand)
    k_cast_f16<<<XN / 4 / 256, 256, 0, stream>>>(x, xinb, XN);

    // 3. x0^T
    const dim3 tgrid(D / 64, D / 64);
    k_transpose<<<tgrid, 256, 0, stream>>>((const u16*)xb0, (u16*)xbTa, D);

    const int ns_grid = (D / 64) * (D / 128);      // 512 blocks, %8==0

    // 4. Newton-Schulz iterations (scaled f16), R11 4-wave ring + 2D XCD chunk
    half_t* cur = xb0;
    half_t* nxt = xb1;
    half_t* Tr  = xbTa;
    half_t* Tw  = xbTb;
    for (int it = 0; it < 10; ++it) {
        gemm_ns<0><<<ns_grid, 256, 0, stream>>>(cur, cur, nullptr, amat, nullptr, D, D, D);
        gemm_ns<1><<<ns_grid, 256, 0, stream>>>(amat, amat, amat, bmat, nullptr, D, D, D);
        if (pingpong) {
            gemm_ns<2><<<ns_grid, 256, 0, stream>>>(bmat, Tr, cur, nxt, Tw, D, D, D);
            half_t* tt = Tr; Tr = Tw; Tw = tt;
        } else {
            gemm_ns<2><<<ns_grid, 256, 0, stream>>>(bmat, Tr, cur, nxt, nullptr, D, D, D);
            k_transpose<<<tgrid, 256, 0, stream>>>((const u16*)nxt, (u16*)Tr, D);
        }
        half_t* t = cur; cur = nxt; nxt = t;
    }

    // 5. out = x @ w_orth + b   (w_orth^T = Tr), 2-blocks/CU dbuf fin
    const int fin_grid = (Bm / 256) * (D / 256);    // 512, %8==0
    gemm_fin<<<fin_grid, 512, 0, stream>>>(xinb, Tr, b, out, Bm, D, D);
}

// Round 15
// 964.435 us; speedup vs baseline: 2.2508x; 2.2508x over previous
//
#include <hip/hip_runtime.h>
#include <stdint.h>

typedef unsigned short u16;
typedef _Float16 half_t;
typedef __attribute__((ext_vector_type(4))) float f32x4;
typedef __attribute__((ext_vector_type(8))) _Float16 f16x8;

#define NS_A 3.4445f
#define NS_B -4.7750f
#define NS_C 2.0315f

// scales (exact powers of 2, folded into epilogues):
//   x stored as 64*x ; a stored as 4096*a ; bmat stored as 4096*bmat
#define SX      64.0f
#define INV_SX  (1.0f / 64.0f)
#define INV_SA  (1.0f / 4096.0f)

// ---- async global->LDS, 16B per lane (wave-uniform LDS base + lane*16 implicit)
typedef const __attribute__((address_space(1))) void* as1_cvp;
typedef __attribute__((address_space(3))) void* as3_vp;
#define GLOAD_LDS16(gp, lp) \
    __builtin_amdgcn_global_load_lds((as1_cvp)(const void*)(gp), (as3_vp)(void*)(lp), 16, 0, 0)

template <int N> __device__ __forceinline__ void vmwait() {
    if constexpr (N == 0)       asm volatile("s_waitcnt vmcnt(0)" ::: "memory");
    else if constexpr (N == 4)  asm volatile("s_waitcnt vmcnt(4)" ::: "memory");
    else if constexpr (N == 6)  asm volatile("s_waitcnt vmcnt(6)" ::: "memory");
    else if constexpr (N == 8)  asm volatile("s_waitcnt vmcnt(8)" ::: "memory");
    else if constexpr (N == 12) asm volatile("s_waitcnt vmcnt(12)" ::: "memory");
    else static_assert(N == 0, "unsupported vmcnt");
}

// =======================================================================
// NS GEMM (modes 0/1/2) — byte-identical to the verified R11 kernel
// (best NS measured: 24.3 us/GEMM). 64x128 block tile, 4 waves (2x2, wave
// 32x64), BK=64, ring R=3 (72 KB -> 2 blocks/CU), 2-D XCD chunk.
// Pipeline per K-step: reads(s); stage(s+2); vmwait(6); barrier;
//                      setprio(1) 16 MFMA setprio(0); barrier.
// LDS XOR swizzle (both-sides, proven 0-conflict).
// =======================================================================
template <int MODE>
__global__ __launch_bounds__(256, 2) void gemm_ns(
    const half_t* __restrict__ A, const half_t* __restrict__ B,
    const half_t* __restrict__ aux,
    void* __restrict__ outp, half_t* __restrict__ outpT,
    int M, int N, int K)
{
    __shared__ half_t As[3][64 * 64];
    __shared__ half_t Bs[3][128 * 64];
    const int tid  = threadIdx.x;
    const int wid  = tid >> 6;
    const int lane = tid & 63;
    const int wr = wid >> 1, wc = wid & 1;

    const int xcd = blockIdx.x & 7;
    const int ii  = blockIdx.x >> 3;               // [0, 64)
    const int brow = ((xcd & 1) * 16 + (ii >> 2)) * 64;
    const int bcol = ((xcd >> 1) * 4 + (ii & 3)) * 128;

    f32x4 acc[2][4] = {};

    const int r0   = tid >> 3;
    const int csrc = ((tid & 7) ^ ((tid >> 3) & 7)) * 8;
    const half_t* gA = A + (size_t)(brow + r0) * K + csrc;
    const half_t* gB = B + (size_t)(bcol + r0) * K + csrc;

    auto stage = [&](int slot, int kt) {
#pragma unroll
        for (int j = 0; j < 2; ++j)   // A: 64 rows
            GLOAD_LDS16(gA + (size_t)(j * 32) * K + kt, &As[slot][(j * 256 + wid * 64) * 8]);
#pragma unroll
        for (int j = 0; j < 4; ++j)   // B: 128 rows
            GLOAD_LDS16(gB + (size_t)(j * 32) * K + kt, &Bs[slot][(j * 256 + wid * 64) * 8]);
    };

    f16x8 af[2][2], bf[4][2];
    auto reads = [&](int slot) {
#pragma unroll
        for (int m = 0; m < 2; ++m) {
            const int row = wr * 32 + m * 16 + (lane & 15);
#pragma unroll
            for (int kk = 0; kk < 2; ++kk) {
                const int cc = (kk * 4 + (lane >> 4)) ^ (row & 7);
                af[m][kk] = *(const f16x8*)&As[slot][row * 64 + cc * 8];
            }
        }
#pragma unroll
        for (int n = 0; n < 4; ++n) {
            const int row = wc * 64 + n * 16 + (lane & 15);
#pragma unroll
            for (int kk = 0; kk < 2; ++kk) {
                const int cc = (kk * 4 + (lane >> 4)) ^ (row & 7);
                bf[n][kk] = *(const f16x8*)&Bs[slot][row * 64 + cc * 8];
            }
        }
    };
    auto mfma = [&]() {
        __builtin_amdgcn_s_setprio(1);
#pragma unroll
        for (int kk = 0; kk < 2; ++kk)
#pragma unroll
            for (int m = 0; m < 2; ++m)
#pragma unroll
                for (int n = 0; n < 4; ++n)
                    acc[m][n] = __builtin_amdgcn_mfma_f32_16x16x32_f16(af[m][kk], bf[n][kk], acc[m][n], 0, 0, 0);
        __builtin_amdgcn_s_setprio(0);
    };

    const int nsteps = K / 64;            // 32
    stage(0, 0);
    stage(1, 64);
    vmwait<6>();                          // certify slot 0
    __builtin_amdgcn_s_barrier();

    int s = 0;
    for (; s < nsteps - 2; ++s) {
        reads(s % 3);
        stage((s + 2) % 3, (s + 2) * 64);
        vmwait<6>();                      // certify slot s+1
        __builtin_amdgcn_s_barrier();
        mfma();
        __builtin_amdgcn_s_barrier();
    }
    reads(s % 3);                         // s = nsteps-2
    vmwait<0>();                          // certify last slot
    __builtin_amdgcn_s_barrier();
    mfma();
    __builtin_amdgcn_s_barrier();
    ++s;
    reads(s % 3);                         // s = nsteps-1
    mfma();

    // epilogue: C/D layout col = lane&15, row = (lane>>4)*4 + r
#pragma unroll
    for (int m = 0; m < 2; ++m) {
#pragma unroll
        for (int n = 0; n < 4; ++n) {
            const int row0 = brow + wr * 32 + m * 16 + (lane >> 4) * 4;
            const int col  = bcol + wc * 64 + n * 16 + (lane & 15);
#pragma unroll
            for (int r = 0; r < 4; ++r) {
                const size_t idx = (size_t)(row0 + r) * N + col;
                const float v = acc[m][n][r];
                if (MODE == 0) {
                    ((half_t*)outp)[idx] = (half_t)v;
                } else if (MODE == 1) {
                    ((half_t*)outp)[idx] = (half_t)(NS_B * (float)aux[idx] + NS_C * v * INV_SA);
                } else {
                    const half_t o = (half_t)(NS_A * (float)aux[idx] + v * INV_SA);
                    ((half_t*)outp)[idx] = o;
                    if (outpT) outpT[(size_t)col * M + row0 + r] = o;
                }
            }
        }
    }
}

// =======================================================================
// Final GEMM R15: out = A@B^T/64 + bias.  256x256 tile, 8 waves (2Mx4N,
// wave 128x64), BK=32, R=2 double-buffer -> 64 KB LDS -> 2 blocks/CU
// co-resident via LDS limit alone. NO min-waves launch_bounds arg (R14's
// (512,4) forced VGPR=64 -> full accumulator spill -> 8x regression).
// Per step s: stage(s+1 -> slot^1) issued FIRST; compute(slot) = 12
// ds_read + setprio 32-MFMA; vmwait(0) + ONE barrier (certify + fence).
// Cross-block TLP covers the drain. Swizzle key (row>>1)&3 (0-conflict).
// =======================================================================
__global__ __launch_bounds__(512) void gemm_fin(
    const half_t* __restrict__ A, const half_t* __restrict__ B,
    const float* __restrict__ bias, float* __restrict__ out,
    int M, int N, int K)
{
    __shared__ half_t As[2][256 * 32];
    __shared__ half_t Bs[2][256 * 32];
    const int tid  = threadIdx.x;
    const int wid  = tid >> 6;
    const int lane = tid & 63;
    const int wm = wid >> 2;
    const int wn = wid & 3;

    int bid = blockIdx.x;                 // gridDim.x % 8 == 0
    const int cpx = gridDim.x >> 3;
    bid = (bid & 7) * cpx + (bid >> 3);
    const int nbx  = N >> 8;
    const int brow = (bid / nbx) << 8;
    const int bcol = (bid % nbx) << 8;

    f32x4 acc[8][4] = {};

    const int r0   = tid >> 2;            // 4 chunks/row
    const int csrc = ((tid & 3) ^ ((tid >> 3) & 3)) * 8;
    const half_t* gA = A + (size_t)(brow + r0) * K + csrc;
    const half_t* gB = B + (size_t)(bcol + r0) * K + csrc;

    auto stage = [&](int slot, int kt) {
#pragma unroll
        for (int j = 0; j < 2; ++j)
            GLOAD_LDS16(gA + (size_t)(j * 128) * K + kt, &As[slot][(j * 512 + wid * 64) * 8]);
#pragma unroll
        for (int j = 0; j < 2; ++j)
            GLOAD_LDS16(gB + (size_t)(j * 128) * K + kt, &Bs[slot][(j * 512 + wid * 64) * 8]);
    };
    auto compute = [&](int slot) {
        f16x8 af[8], bf[4];
#pragma unroll
        for (int fr = 0; fr < 8; ++fr) {
            const int row = wm * 128 + fr * 16 + (lane & 15);
            af[fr] = *(const f16x8*)&As[slot][row * 32 + (((lane >> 4) ^ ((row >> 1) & 3)) * 8)];
        }
#pragma unroll
        for (int fc = 0; fc < 4; ++fc) {
            const int row = wn * 64 + fc * 16 + (lane & 15);
            bf[fc] = *(const f16x8*)&Bs[slot][row * 32 + (((lane >> 4) ^ ((row >> 1) & 3)) * 8)];
        }
        __builtin_amdgcn_s_setprio(1);
#pragma unroll
        for (int fr = 0; fr < 8; ++fr)
#pragma unroll
            for (int fc = 0; fc < 4; ++fc)
                acc[fr][fc] = __builtin_amdgcn_mfma_f32_16x16x32_f16(af[fr], bf[fc], acc[fr][fc], 0, 0, 0);
        __builtin_amdgcn_s_setprio(0);
    };

    const int nsteps = K >> 5;            // 64
    stage(0, 0);
    vmwait<0>();                          // certify slot 0
    __builtin_amdgcn_s_barrier();

    for (int s = 0; s < nsteps; ++s) {
        const int slot = s & 1;
        if (s + 1 < nsteps) stage(slot ^ 1, (s + 1) * 32);  // issue early
        compute(slot);
        if (s + 1 < nsteps) {
            vmwait<0>();                  // certify slot^1 (issued ~compute ago)
            __builtin_amdgcn_s_barrier(); // + fence this slot's reads
        }
    }

    // epilogue
#pragma unroll
    for (int fr = 0; fr < 8; ++fr) {
#pragma unroll
        for (int fc = 0; fc < 4; ++fc) {
            const int row0 = brow + wm * 128 + fr * 16 + (lane >> 4) * 4;
            const int col  = bcol + wn * 64 + fc * 16 + (lane & 15);
            const float bv = bias[col];
#pragma unroll
            for (int r = 0; r < 4; ++r)
                out[(size_t)(row0 + r) * N + col] = acc[fr][fc][r] * INV_SX + bv;
        }
    }
}

// ---- deterministic Frobenius-norm reduction (fixed order, no float atomics)
__global__ __launch_bounds__(256) void k_sumsq(const float* __restrict__ w,
                                               float* __restrict__ part, int n) {
    __shared__ float s[256];
    const int per  = n / 1024;
    const int base = blockIdx.x * per;
    float acc = 0.f;
    for (int i = threadIdx.x; i < per; i += 256) {
        float v = w[base + i];
        acc += v * v;
    }
    s[threadIdx.x] = acc;
    __syncthreads();
    for (int k = 128; k > 0; k >>= 1) {
        if (threadIdx.x < k) s[threadIdx.x] += s[threadIdx.x + k];
        __syncthreads();
    }
    if (threadIdx.x == 0) part[blockIdx.x] = s[0];
}

__global__ __launch_bounds__(256) void k_scalefin(const float* __restrict__ part,
                                                  float* __restrict__ scale) {
    __shared__ float s[256];
    float acc = 0.f;
    for (int i = threadIdx.x; i < 1024; i += 256) acc += part[i];
    s[threadIdx.x] = acc;
    __syncthreads();
    for (int k = 128; k > 0; k >>= 1) {
        if (threadIdx.x < k) s[threadIdx.x] += s[threadIdx.x + k];
        __syncthreads();
    }
    if (threadIdx.x == 0) scale[0] = SX / (sqrtf(s[0]) + 1e-7f);
}

// ---- x0_s = w * (64/(|w|+eps)) -> f16
__global__ __launch_bounds__(256) void k_scale_f16(const float* __restrict__ w,
                                                   const float* __restrict__ scale,
                                                   half_t* __restrict__ o, int n) {
    const int i = (blockIdx.x * 256 + threadIdx.x) * 4;
    if (i < n) {
        const float sc = scale[0];
        float4 v = *(const float4*)(w + i);
        o[i + 0] = (half_t)(v.x * sc);
        o[i + 1] = (half_t)(v.y * sc);
        o[i + 2] = (half_t)(v.z * sc);
        o[i + 3] = (half_t)(v.w * sc);
    }
}

// ---- f32 -> f16 cast
__global__ __launch_bounds__(256) void k_cast_f16(const float* __restrict__ w,
                                                  half_t* __restrict__ o, int n) {
    const int i = (blockIdx.x * 256 + threadIdx.x) * 4;
    if (i < n) {
        float4 v = *(const float4*)(w + i);
        o[i + 0] = (half_t)v.x;
        o[i + 1] = (half_t)v.y;
        o[i + 2] = (half_t)v.z;
        o[i + 3] = (half_t)v.w;
    }
}

// ---- 16-bit NxN transpose, 64x64 LDS tiles (+1 pad)
__global__ __launch_bounds__(256) void k_transpose(const u16* __restrict__ in,
                                                   u16* __restrict__ out, int n) {
    __shared__ u16 tile[64][65];
    const int bx = blockIdx.x * 64, by = blockIdx.y * 64;
    const int tx = threadIdx.x & 63, ty = threadIdx.x >> 6;
    for (int i = ty; i < 64; i += 4) tile[i][tx] = in[(size_t)(by + i) * n + bx + tx];
    __syncthreads();
    for (int i = ty; i < 64; i += 4) out[(size_t)(bx + i) * n + by + tx] = tile[tx][i];
}

extern "C" void kernel_launch(void* const* d_in, const int* in_sizes, int n_in,
                              void* d_out, int out_size, void* d_ws, size_t ws_size,
                              hipStream_t stream) {
    const float* x = (const float*)d_in[0];
    const float* w = (const float*)d_in[1];
    const float* b = (const float*)d_in[2];
    float* out = (float*)d_out;

    const int D  = 2048;
    const int Bm = in_sizes[0] / D;      // 16384
    const int WN = D * D;
    const int XN = Bm * D;

    const size_t matB = (size_t)WN * 2;
    const bool pingpong = ws_size >= 8192 + 6 * matB + (size_t)XN * 2;

    char* ws = (char*)d_ws;
    float* part  = (float*)ws;
    float* scale = part + 1024;
    half_t* xb0  = (half_t*)(ws + 8192);
    half_t* xb1  = xb0 + WN;
    half_t* xbTa = xb1 + WN;
    half_t* xbTb = pingpong ? (xbTa + WN) : xbTa;
    half_t* amat = xbTb + WN;
    half_t* bmat = amat + WN;
    half_t* xinb = bmat + WN;

    // 1. frobenius norm -> scale; x0_s = 64*w/(|w|+eps) in f16
    k_sumsq<<<1024, 256, 0, stream>>>(w, part, WN);
    k_scalefin<<<1, 256, 0, stream>>>(part, scale);
    k_scale_f16<<<WN / 4 / 256, 256, 0, stream>>>(w, scale, xb0, WN);

    // 2. x -> f16 (final GEMM operand)
    k_cast_f16<<<XN / 4 / 256, 256, 0, stream>>>(x, xinb, XN);

    // 3. x0^T
    const dim3 tgrid(D / 64, D / 64);
    k_transpose<<<tgrid, 256, 0, stream>>>((const u16*)xb0, (u16*)xbTa, D);

    const int ns_grid = (D / 64) * (D / 128);      // 512 blocks, %8==0

    // 4. Newton-Schulz iterations (scaled f16), R11 4-wave ring + 2D XCD chunk
    half_t* cur = xb0;
    half_t* nxt = xb1;
    half_t* Tr  = xbTa;
    half_t* Tw  = xbTb;
    for (int it = 0; it < 10; ++it) {
        gemm_ns<0><<<ns_grid, 256, 0, stream>>>(cur, cur, nullptr, amat, nullptr, D, D, D);
        gemm_ns<1><<<ns_grid, 256, 0, stream>>>(amat, amat, amat, bmat, nullptr, D, D, D);
        if (pingpong) {
            gemm_ns<2><<<ns_grid, 256, 0, stream>>>(bmat, Tr, cur, nxt, Tw, D, D, D);
            half_t* tt = Tr; Tr = Tw; Tw = tt;
        } else {
            gemm_ns<2><<<ns_grid, 256, 0, stream>>>(bmat, Tr, cur, nxt, nullptr, D, D, D);
            k_transpose<<<tgrid, 256, 0, stream>>>((const u16*)nxt, (u16*)Tr, D);
        }
        half_t* t = cur; cur = nxt; nxt = t;
    }

    // 5. out = x @ w_orth + b   (w_orth^T = Tr), 2-blocks/CU dbuf fin
    const int fin_grid = (Bm / 256) * (D / 256);    // 512, %8==0
    gemm_fin<<<fin_grid, 512, 0, stream>>>(xinb, Tr, b, out, Bm, D, D);
}

// Round 16
// 943.193 us; speedup vs baseline: 2.3015x; 1.0225x over previous
//
#include <hip/hip_runtime.h>
#include <stdint.h>

typedef unsigned short u16;
typedef _Float16 half_t;
typedef __attribute__((ext_vector_type(4))) float f32x4;
typedef __attribute__((ext_vector_type(8))) _Float16 f16x8;

#define NS_A 3.4445f
#define NS_B -4.7750f
#define NS_C 2.0315f

// scales (exact powers of 2, folded into epilogues):
//   x stored as 64*x ; a stored as 4096*a ; bmat stored as 4096*bmat
#define SX      64.0f
#define INV_SX  (1.0f / 64.0f)
#define INV_SA  (1.0f / 4096.0f)

// ---- async global->LDS, 16B per lane (wave-uniform LDS base + lane*16 implicit)
typedef const __attribute__((address_space(1))) void* as1_cvp;
typedef __attribute__((address_space(3))) void* as3_vp;
#define GLOAD_LDS16(gp, lp) \
    __builtin_amdgcn_global_load_lds((as1_cvp)(const void*)(gp), (as3_vp)(void*)(lp), 16, 0, 0)

template <int N> __device__ __forceinline__ void vmwait() {
    if constexpr (N == 0)       asm volatile("s_waitcnt vmcnt(0)" ::: "memory");
    else if constexpr (N == 6)  asm volatile("s_waitcnt vmcnt(6)" ::: "memory");
    else static_assert(N == 0, "unsupported vmcnt");
}

// =======================================================================
// NS GEMM (modes 0/1/2) — byte-identical to the verified R11 kernel
// (best NS measured: 24.3 us/GEMM). 64x128 block tile, 4 waves (2x2, wave
// 32x64), BK=64, ring R=3 (72 KB -> 2 blocks/CU), 2-D XCD chunk.
// Pipeline per K-step: reads(s); stage(s+2); vmwait(6); barrier;
//                      setprio(1) 16 MFMA setprio(0); barrier.
// LDS XOR swizzle (both-sides, proven 0-conflict).
// MODE 2 with outp==nullptr skips the untransposed write (last iteration:
// only x'^T feeds the final GEMM).
// =======================================================================
template <int MODE>
__global__ __launch_bounds__(256, 2) void gemm_ns(
    const half_t* __restrict__ A, const half_t* __restrict__ B,
    const half_t* __restrict__ aux,
    void* __restrict__ outp, half_t* __restrict__ outpT,
    int M, int N, int K)
{
    __shared__ half_t As[3][64 * 64];
    __shared__ half_t Bs[3][128 * 64];
    const int tid  = threadIdx.x;
    const int wid  = tid >> 6;
    const int lane = tid & 63;
    const int wr = wid >> 1, wc = wid & 1;

    const int xcd = blockIdx.x & 7;
    const int ii  = blockIdx.x >> 3;               // [0, 64)
    const int brow = ((xcd & 1) * 16 + (ii >> 2)) * 64;
    const int bcol = ((xcd >> 1) * 4 + (ii & 3)) * 128;

    f32x4 acc[2][4] = {};

    const int r0   = tid >> 3;
    const int csrc = ((tid & 7) ^ ((tid >> 3) & 7)) * 8;
    const half_t* gA = A + (size_t)(brow + r0) * K + csrc;
    const half_t* gB = B + (size_t)(bcol + r0) * K + csrc;

    auto stage = [&](int slot, int kt) {
#pragma unroll
        for (int j = 0; j < 2; ++j)   // A: 64 rows
            GLOAD_LDS16(gA + (size_t)(j * 32) * K + kt, &As[slot][(j * 256 + wid * 64) * 8]);
#pragma unroll
        for (int j = 0; j < 4; ++j)   // B: 128 rows
            GLOAD_LDS16(gB + (size_t)(j * 32) * K + kt, &Bs[slot][(j * 256 + wid * 64) * 8]);
    };

    f16x8 af[2][2], bf[4][2];
    auto reads = [&](int slot) {
#pragma unroll
        for (int m = 0; m < 2; ++m) {
            const int row = wr * 32 + m * 16 + (lane & 15);
#pragma unroll
            for (int kk = 0; kk < 2; ++kk) {
                const int cc = (kk * 4 + (lane >> 4)) ^ (row & 7);
                af[m][kk] = *(const f16x8*)&As[slot][row * 64 + cc * 8];
            }
        }
#pragma unroll
        for (int n = 0; n < 4; ++n) {
            const int row = wc * 64 + n * 16 + (lane & 15);
#pragma unroll
            for (int kk = 0; kk < 2; ++kk) {
                const int cc = (kk * 4 + (lane >> 4)) ^ (row & 7);
                bf[n][kk] = *(const f16x8*)&Bs[slot][row * 64 + cc * 8];
            }
        }
    };
    auto mfma = [&]() {
        __builtin_amdgcn_s_setprio(1);
#pragma unroll
        for (int kk = 0; kk < 2; ++kk)
#pragma unroll
            for (int m = 0; m < 2; ++m)
#pragma unroll
                for (int n = 0; n < 4; ++n)
                    acc[m][n] = __builtin_amdgcn_mfma_f32_16x16x32_f16(af[m][kk], bf[n][kk], acc[m][n], 0, 0, 0);
        __builtin_amdgcn_s_setprio(0);
    };

    const int nsteps = K / 64;            // 32
    stage(0, 0);
    stage(1, 64);
    vmwait<6>();                          // certify slot 0
    __builtin_amdgcn_s_barrier();

    int s = 0;
    for (; s < nsteps - 2; ++s) {
        reads(s % 3);
        stage((s + 2) % 3, (s + 2) * 64);
        vmwait<6>();                      // certify slot s+1
        __builtin_amdgcn_s_barrier();
        mfma();
        __builtin_amdgcn_s_barrier();
    }
    reads(s % 3);                         // s = nsteps-2
    vmwait<0>();                          // certify last slot
    __builtin_amdgcn_s_barrier();
    mfma();
    __builtin_amdgcn_s_barrier();
    ++s;
    reads(s % 3);                         // s = nsteps-1
    mfma();

    // epilogue: C/D layout col = lane&15, row = (lane>>4)*4 + r
#pragma unroll
    for (int m = 0; m < 2; ++m) {
#pragma unroll
        for (int n = 0; n < 4; ++n) {
            const int row0 = brow + wr * 32 + m * 16 + (lane >> 4) * 4;
            const int col  = bcol + wc * 64 + n * 16 + (lane & 15);
#pragma unroll
            for (int r = 0; r < 4; ++r) {
                const size_t idx = (size_t)(row0 + r) * N + col;
                const float v = acc[m][n][r];
                if (MODE == 0) {
                    ((half_t*)outp)[idx] = (half_t)v;
                } else if (MODE == 1) {
                    ((half_t*)outp)[idx] = (half_t)(NS_B * (float)aux[idx] + NS_C * v * INV_SA);
                } else {
                    const half_t o = (half_t)(NS_A * (float)aux[idx] + v * INV_SA);
                    if (outp)  ((half_t*)outp)[idx] = o;
                    if (outpT) outpT[(size_t)col * M + row0 + r] = o;
                }
            }
        }
    }
}

// =======================================================================
// Final GEMM R16: out = A@B^T/64 + bias.  256x256 tile, 8 waves (2Mx4N,
// wave 128x64), BK=64 (64 MFMA/wave/step: per-SIMD compute ~2480 cyc >>
// ~900-cyc HBM latency, so the per-step vmwait(0) is nearly free — fixes
// R15's BK=32 exposure), R=2 double-buffer (128 KB LDS), ONE barrier per
// step (half the R8 ring's count). No launch-bounds min (R14 spill lesson);
// est ~245 VGPR, no spill. Swizzle: 8 chunks/row, key (row&7) — the proven
// BK=64 0-conflict pattern. Race proof: reads(s) consumed by mfma before
// the end barrier; stage(s+1) overwrites slot^1 only after that barrier.
// =======================================================================
__global__ __launch_bounds__(512) void gemm_fin(
    const half_t* __restrict__ A, const half_t* __restrict__ B,
    const float* __restrict__ bias, float* __restrict__ out,
    int M, int N, int K)
{
    __shared__ half_t As[2][256 * 64];
    __shared__ half_t Bs[2][256 * 64];
    const int tid  = threadIdx.x;
    const int wid  = tid >> 6;
    const int lane = tid & 63;
    const int wm = wid >> 2;
    const int wn = wid & 3;

    int bid = blockIdx.x;                 // gridDim.x % 8 == 0
    const int cpx = gridDim.x >> 3;
    bid = (bid & 7) * cpx + (bid >> 3);
    const int nbx  = N >> 8;
    const int brow = (bid / nbx) << 8;
    const int bcol = (bid % nbx) << 8;

    f32x4 acc[8][4] = {};

    // staging: 8 chunks of 16B per 64-f16 row; chunk c = j*512 + tid
    //   row = j*64 + (tid>>3), chunk-col = tid&7; source pre-XOR (row&7)
    const int r0   = tid >> 3;
    const int csrc = ((tid & 7) ^ ((tid >> 3) & 7)) * 8;
    const half_t* gA = A + (size_t)(brow + r0) * K + csrc;
    const half_t* gB = B + (size_t)(bcol + r0) * K + csrc;

    auto stage = [&](int slot, int kt) {
#pragma unroll
        for (int j = 0; j < 4; ++j)   // A: 256 rows = 2048 chunks
            GLOAD_LDS16(gA + (size_t)(j * 64) * K + kt, &As[slot][(j * 512 + wid * 64) * 8]);
#pragma unroll
        for (int j = 0; j < 4; ++j)   // B: 256 rows
            GLOAD_LDS16(gB + (size_t)(j * 64) * K + kt, &Bs[slot][(j * 512 + wid * 64) * 8]);
    };
    auto compute = [&](int slot) {
        f16x8 af[8][2], bf[4][2];
#pragma unroll
        for (int fr = 0; fr < 8; ++fr) {
            const int row = wm * 128 + fr * 16 + (lane & 15);
#pragma unroll
            for (int kk = 0; kk < 2; ++kk) {
                const int cc = (kk * 4 + (lane >> 4)) ^ (row & 7);
                af[fr][kk] = *(const f16x8*)&As[slot][row * 64 + cc * 8];
            }
        }
#pragma unroll
        for (int fc = 0; fc < 4; ++fc) {
            const int row = wn * 64 + fc * 16 + (lane & 15);
#pragma unroll
            for (int kk = 0; kk < 2; ++kk) {
                const int cc = (kk * 4 + (lane >> 4)) ^ (row & 7);
                bf[fc][kk] = *(const f16x8*)&Bs[slot][row * 64 + cc * 8];
            }
        }
        __builtin_amdgcn_s_setprio(1);
#pragma unroll
        for (int kk = 0; kk < 2; ++kk)
#pragma unroll
            for (int fr = 0; fr < 8; ++fr)
#pragma unroll
                for (int fc = 0; fc < 4; ++fc)
                    acc[fr][fc] = __builtin_amdgcn_mfma_f32_16x16x32_f16(af[fr][kk], bf[fc][kk], acc[fr][fc], 0, 0, 0);
        __builtin_amdgcn_s_setprio(0);
    };

    const int nsteps = K >> 6;            // 32
    stage(0, 0);
    vmwait<0>();                          // certify slot 0
    __builtin_amdgcn_s_barrier();

    for (int s = 0; s < nsteps; ++s) {
        const int slot = s & 1;
        if (s + 1 < nsteps) stage(slot ^ 1, (s + 1) * 64);  // issue early
        compute(slot);                    // ~2480 cyc/SIMD covers stage latency
        if (s + 1 < nsteps) {
            vmwait<0>();                  // certify slot^1 (nearly free)
            __builtin_amdgcn_s_barrier(); // + fence this slot's reads
        }
    }

    // epilogue
#pragma unroll
    for (int fr = 0; fr < 8; ++fr) {
#pragma unroll
        for (int fc = 0; fc < 4; ++fc) {
            const int row0 = brow + wm * 128 + fr * 16 + (lane >> 4) * 4;
            const int col  = bcol + wn * 64 + fc * 16 + (lane & 15);
            const float bv = bias[col];
#pragma unroll
            for (int r = 0; r < 4; ++r)
                out[(size_t)(row0 + r) * N + col] = acc[fr][fc][r] * INV_SX + bv;
        }
    }
}

// ---- deterministic Frobenius-norm reduction (fixed order, no float atomics)
__global__ __launch_bounds__(256) void k_sumsq(const float* __restrict__ w,
                                               float* __restrict__ part, int n) {
    __shared__ float s[256];
    const int per  = n / 1024;
    const int base = blockIdx.x * per;
    float acc = 0.f;
    for (int i = threadIdx.x; i < per; i += 256) {
        float v = w[base + i];
        acc += v * v;
    }
    s[threadIdx.x] = acc;
    __syncthreads();
    for (int k = 128; k > 0; k >>= 1) {
        if (threadIdx.x < k) s[threadIdx.x] += s[threadIdx.x + k];
        __syncthreads();
    }
    if (threadIdx.x == 0) part[blockIdx.x] = s[0];
}

__global__ __launch_bounds__(256) void k_scalefin(const float* __restrict__ part,
                                                  float* __restrict__ scale) {
    __shared__ float s[256];
    float acc = 0.f;
    for (int i = threadIdx.x; i < 1024; i += 256) acc += part[i];
    s[threadIdx.x] = acc;
    __syncthreads();
    for (int k = 128; k > 0; k >>= 1) {
        if (threadIdx.x < k) s[threadIdx.x] += s[threadIdx.x + k];
        __syncthreads();
    }
    if (threadIdx.x == 0) scale[0] = SX / (sqrtf(s[0]) + 1e-7f);
}

// ---- fused: x0 = 64*w/(|w|+eps) -> f16, writing BOTH x0 and x0^T
__global__ __launch_bounds__(256) void k_scale_tr(const float* __restrict__ w,
                                                  const float* __restrict__ scale,
                                                  u16* __restrict__ o,
                                                  u16* __restrict__ oT, int n) {
    __shared__ u16 tile[64][65];
    const int bx = blockIdx.x * 64, by = blockIdx.y * 64;
    const int tx = threadIdx.x & 63, ty = threadIdx.x >> 6;
    const float sc = scale[0];
    for (int i = ty; i < 64; i += 4) {
        const half_t h = (half_t)(w[(size_t)(by + i) * n + bx + tx] * sc);
        const u16 u = __builtin_bit_cast(u16, h);
        o[(size_t)(by + i) * n + bx + tx] = u;
        tile[i][tx] = u;
    }
    __syncthreads();
    for (int i = ty; i < 64; i += 4)
        oT[(size_t)(bx + i) * n + by + tx] = tile[tx][i];
}

// ---- f32 -> f16 cast
__global__ __launch_bounds__(256) void k_cast_f16(const float* __restrict__ w,
                                                  half_t* __restrict__ o, int n) {
    const int i = (blockIdx.x * 256 + threadIdx.x) * 4;
    if (i < n) {
        float4 v = *(const float4*)(w + i);
        o[i + 0] = (half_t)v.x;
        o[i + 1] = (half_t)v.y;
        o[i + 2] = (half_t)v.z;
        o[i + 3] = (half_t)v.w;
    }
}

// ---- 16-bit NxN transpose, 64x64 LDS tiles (+1 pad) — non-pingpong fallback
__global__ __launch_bounds__(256) void k_transpose(const u16* __restrict__ in,
                                                   u16* __restrict__ out, int n) {
    __shared__ u16 tile[64][65];
    const int bx = blockIdx.x * 64, by = blockIdx.y * 64;
    const int tx = threadIdx.x & 63, ty = threadIdx.x >> 6;
    for (int i = ty; i < 64; i += 4) tile[i][tx] = in[(size_t)(by + i) * n + bx + tx];
    __syncthreads();
    for (int i = ty; i < 64; i += 4) out[(size_t)(bx + i) * n + by + tx] = tile[tx][i];
}

extern "C" void kernel_launch(void* const* d_in, const int* in_sizes, int n_in,
                              void* d_out, int out_size, void* d_ws, size_t ws_size,
                              hipStream_t stream) {
    const float* x = (const float*)d_in[0];
    const float* w = (const float*)d_in[1];
    const float* b = (const float*)d_in[2];
    float* out = (float*)d_out;

    const int D  = 2048;
    const int Bm = in_sizes[0] / D;      // 16384
    const int WN = D * D;
    const int XN = Bm * D;

    const size_t matB = (size_t)WN * 2;
    const bool pingpong = ws_size >= 8192 + 6 * matB + (size_t)XN * 2;

    char* ws = (char*)d_ws;
    float* part  = (float*)ws;
    float* scale = part + 1024;
    half_t* xb0  = (half_t*)(ws + 8192);
    half_t* xb1  = xb0 + WN;
    half_t* xbTa = xb1 + WN;
    half_t* xbTb = pingpong ? (xbTa + WN) : xbTa;
    half_t* amat = xbTb + WN;
    half_t* bmat = amat + WN;
    half_t* xinb = bmat + WN;

    // 1. frobenius norm -> scale; x0 = 64*w/(|w|+eps) -> f16 (+ fused x0^T)
    k_sumsq<<<1024, 256, 0, stream>>>(w, part, WN);
    k_scalefin<<<1, 256, 0, stream>>>(part, scale);
    const dim3 tgrid(D / 64, D / 64);
    k_scale_tr<<<tgrid, 256, 0, stream>>>(w, scale, (u16*)xb0, (u16*)xbTa, D);

    // 2. x -> f16 (final GEMM operand)
    k_cast_f16<<<XN / 4 / 256, 256, 0, stream>>>(x, xinb, XN);

    const int ns_grid = (D / 64) * (D / 128);      // 512 blocks, %8==0

    // 3. Newton-Schulz iterations (scaled f16), R11 4-wave ring + 2D XCD chunk
    half_t* cur = xb0;
    half_t* nxt = xb1;
    half_t* Tr  = xbTa;
    half_t* Tw  = xbTb;
    for (int it = 0; it < 10; ++it) {
        gemm_ns<0><<<ns_grid, 256, 0, stream>>>(cur, cur, nullptr, amat, nullptr, D, D, D);
        gemm_ns<1><<<ns_grid, 256, 0, stream>>>(amat, amat, amat, bmat, nullptr, D, D, D);
        if (pingpong) {
            // last iteration: only x'^T is consumed downstream
            half_t* outp = (it == 9) ? nullptr : nxt;
            gemm_ns<2><<<ns_grid, 256, 0, stream>>>(bmat, Tr, cur, outp, Tw, D, D, D);
            half_t* tt = Tr; Tr = Tw; Tw = tt;
        } else {
            gemm_ns<2><<<ns_grid, 256, 0, stream>>>(bmat, Tr, cur, nxt, nullptr, D, D, D);
            k_transpose<<<tgrid, 256, 0, stream>>>((const u16*)nxt, (u16*)Tr, D);
        }
        half_t* t = cur; cur = nxt; nxt = t;
    }

    // 4. out = x @ w_orth + b   (w_orth^T = Tr), BK=64 dbuf fin
    const int fin_grid = (Bm / 256) * (D / 256);    // 512, %8==0
    gemm_fin<<<fin_grid, 512, 0, stream>>>(xinb, Tr, b, out, Bm, D, D);
}